// Round 1
// baseline (395.477 us; speedup 1.0000x reference)
//
#include <hip/hip_runtime.h>

typedef unsigned short u16;
typedef unsigned int   u32;
typedef __bf16 bf16;
typedef bf16  bf16x8 __attribute__((ext_vector_type(8)));
typedef u16   u16x8  __attribute__((ext_vector_type(8)));
typedef float f32x4  __attribute__((ext_vector_type(4)));

__device__ __forceinline__ u16 f2bf(float f) {
  u32 u = __builtin_bit_cast(u32, f);
  u32 r = u + 0x7fffu + ((u >> 16) & 1u);
  return (u16)(r >> 16);
}

__device__ __forceinline__ bf16x8 ldb8(const u16* p) {
  return __builtin_bit_cast(bf16x8, *reinterpret_cast<const u16x8*>(p));
}

__device__ __forceinline__ f32x4 mfma16(bf16x8 a, bf16x8 b, f32x4 c) {
  return __builtin_amdgcn_mfma_f32_16x16x32_bf16(a, b, c, 0, 0, 0);
}

// ---------------- fp32 -> bf16 conversion ----------------
__global__ void cvt_bf16(const float* __restrict__ in, u16* __restrict__ out, int n4) {
  int stride = gridDim.x * blockDim.x;
  for (int i = blockIdx.x * blockDim.x + threadIdx.x; i < n4; i += stride) {
    float4 f = reinterpret_cast<const float4*>(in)[i];
    ushort4 o;
    o.x = f2bf(f.x); o.y = f2bf(f.y); o.z = f2bf(f.z); o.w = f2bf(f.w);
    reinterpret_cast<ushort4*>(out)[i] = o;
  }
}

// ---------------- RoPE tables: [2048][32] cos/sin ----------------
__global__ void rope_tab(float* __restrict__ ct, float* __restrict__ st) {
  int idx = blockIdx.x * 256 + threadIdx.x;   // 65536 total
  int t = idx >> 5, i = idx & 31;
  // theta_i = 10000^(-i/32) = 2^(-i * log2(1e4)/32)
  float theta = exp2f(-(float)i * 0.4152410118609203f);
  float ang = (float)t * theta;
  ct[idx] = cosf(ang);
  st[idx] = sinf(ang);
}

// ---------------- QKV GEMM (8192x3072x1024) + fused RoPE epilogue ----------------
// C[m][n] = sum_k X[m][k] * Wqkv[n][k]; n<1024 -> q (rope), <2048 -> k (rope), else v.
__global__ __launch_bounds__(256) void gemm_qkv(
    const u16* __restrict__ xb, const u16* __restrict__ wb,
    u16* __restrict__ qb, u16* __restrict__ kb, u16* __restrict__ vb,
    const float* __restrict__ cost, const float* __restrict__ sint) {
  __shared__ u16 As[128][72];
  __shared__ u16 Bs[128][72];
  int tid = threadIdx.x, lane = tid & 63, w = tid >> 6;
  int wm = w >> 1, wn = w & 1;
  int lr = lane & 15, lk = lane >> 4;
  int m0 = blockIdx.y * 128, n0 = blockIdx.x * 128;

  f32x4 acc[4][4] = {};

  for (int k0 = 0; k0 < 1024; k0 += 64) {
#pragma unroll
    for (int i = 0; i < 4; i++) {
      int c = tid + 256 * i;
      int r = c >> 3, col = (c & 7) * 8;
      *reinterpret_cast<u16x8*>(&As[r][col]) =
          *reinterpret_cast<const u16x8*>(&xb[(size_t)(m0 + r) * 1024 + k0 + col]);
      *reinterpret_cast<u16x8*>(&Bs[r][col]) =
          *reinterpret_cast<const u16x8*>(&wb[(size_t)(n0 + r) * 1024 + k0 + col]);
    }
    __syncthreads();
#pragma unroll
    for (int kk = 0; kk < 2; kk++) {
      bf16x8 af[4], bfr[4];
#pragma unroll
      for (int mt = 0; mt < 4; mt++) af[mt]  = ldb8(&As[64 * wm + 16 * mt + lr][lk * 8 + 32 * kk]);
#pragma unroll
      for (int nt = 0; nt < 4; nt++) bfr[nt] = ldb8(&Bs[64 * wn + 16 * nt + lr][lk * 8 + 32 * kk]);
#pragma unroll
      for (int mt = 0; mt < 4; mt++)
#pragma unroll
        for (int nt = 0; nt < 4; nt++)
          acc[mt][nt] = mfma16(af[mt], bfr[nt], acc[mt][nt]);
    }
    __syncthreads();
  }

  // epilogue: C/D layout col = lane&15, row = (lane>>4)*4 + reg
#pragma unroll
  for (int nt = 0; nt < 4; nt++) {
    int col = n0 + 64 * wn + 16 * nt + lr;
    int sec = col >> 10;            // 0=q 1=k 2=v
    int cc = col & 1023;
    int h = cc >> 6, d = cc & 63;
    u16* buf = (sec == 0) ? qb : ((sec == 1) ? kb : vb);
#pragma unroll
    for (int mt = 0; mt < 4; mt++) {
      int Mb = m0 + 64 * wm + 16 * mt + lk * 4;
#pragma unroll
      for (int r = 0; r < 4; r++) {
        int M = Mb + r;
        int b = M >> 11, t = M & 2047;
        float val = acc[mt][nt][r];
        float par = __shfl_xor(val, 1);   // partner column (d^1)
        float res;
        if (sec < 2) {
          float c_ = cost[t * 32 + (d >> 1)];
          float s_ = sint[t * 32 + (d >> 1)];
          res = (d & 1) ? (val * c_ + par * s_) : (val * c_ - par * s_);
        } else {
          res = val;
        }
        buf[((size_t)(b * 16 + h) * 2048 + t) * 64 + d] = f2bf(res);
      }
    }
  }
}

// ---------------- V transpose: (bh, t, d) -> (bh, d, t) ----------------
__global__ __launch_bounds__(256) void transpose_v(const u16* __restrict__ v_buf,
                                                   u16* __restrict__ vt_buf) {
  __shared__ u16 tile[64][72];
  int bh = blockIdx.y, t0 = blockIdx.x * 64;
  const u16* src = v_buf + ((size_t)bh * 2048 + t0) * 64;
#pragma unroll
  for (int i = 0; i < 2; i++) {
    int c = threadIdx.x + 256 * i;
    int r = c >> 3, col = (c & 7) * 8;
    *reinterpret_cast<u16x8*>(&tile[r][col]) =
        *reinterpret_cast<const u16x8*>(&src[r * 64 + col]);
  }
  __syncthreads();
  u16* dst = vt_buf + (size_t)bh * 64 * 2048 + t0;
#pragma unroll
  for (int i = 0; i < 2; i++) {
    int c = threadIdx.x + 256 * i;
    int d = c >> 3, tt = (c & 7) * 8;
    u16x8 o;
#pragma unroll
    for (int j = 0; j < 8; j++) o[j] = tile[tt + j][d];
    *reinterpret_cast<u16x8*>(&dst[(size_t)d * 2048 + tt]) = o;
  }
}

// ---------------- Flash attention (causal), 64 q-rows/block, KV tile 64 ----------------
__global__ __launch_bounds__(256) void attn_fwd(
    const u16* __restrict__ qg, const u16* __restrict__ kg,
    const u16* __restrict__ vtg, u16* __restrict__ og) {
  __shared__ u16 Ks[64][72];        // [kv][d]
  __shared__ u16 Vs[64][72];        // transposed: [d][kv]
  __shared__ u16 Ps[4][16][72];     // per-wave P tile [q][kv]
  int tid = threadIdx.x, lane = tid & 63, w = tid >> 6;
  int lr = lane & 15, lk = lane >> 4;
  int bh = blockIdx.y;
  int qt = blockIdx.x;
  int q0 = qt * 64;
  const u16* qb  = qg  + (size_t)bh * 2048 * 64;
  const u16* kb  = kg  + (size_t)bh * 2048 * 64;
  const u16* vtb = vtg + (size_t)bh * 64 * 2048;

  // Q fragments: A layout row = lane&15, k = (lane>>4)*8 + j  (+32 per slice)
  int qrow = q0 + 16 * w + lr;
  bf16x8 qf0 = ldb8(&qb[(size_t)qrow * 64 + lk * 8]);
  bf16x8 qf1 = ldb8(&qb[(size_t)qrow * 64 + lk * 8 + 32]);

  f32x4 o[4] = {};
  float m_[4], l_[4];
#pragma unroll
  for (int r = 0; r < 4; r++) { m_[r] = -3.0e38f; l_[r] = 0.f; }

  const float C = 0.18033688011112042f;   // 0.125 / ln(2)

  for (int kt = 0; kt <= qt; kt++) {
    int k0 = kt * 64;
    // stage K (row-major [kv][d]) and V^T (row-major [d][kv])
#pragma unroll
    for (int i = 0; i < 2; i++) {
      int c = tid + 256 * i;
      int r = c >> 3, col = (c & 7) * 8;
      *reinterpret_cast<u16x8*>(&Ks[r][col]) =
          *reinterpret_cast<const u16x8*>(&kb[(size_t)(k0 + r) * 64 + col]);
      *reinterpret_cast<u16x8*>(&Vs[r][col]) =
          *reinterpret_cast<const u16x8*>(&vtb[(size_t)r * 2048 + k0 + col]);
    }
    __syncthreads();

    // S = Q K^T  (per wave: 16 q-rows x 64 k-cols)
    f32x4 s[4];
#pragma unroll
    for (int ct = 0; ct < 4; ct++) {
      bf16x8 kf0 = ldb8(&Ks[16 * ct + lr][lk * 8]);
      bf16x8 kf1 = ldb8(&Ks[16 * ct + lr][lk * 8 + 32]);
      f32x4 z = {};
      z = mfma16(qf0, kf0, z);
      z = mfma16(qf1, kf1, z);
      s[ct] = z;
    }

    if (k0 == q0) {   // diagonal tile: causal mask
#pragma unroll
      for (int ct = 0; ct < 4; ct++) {
        int kglob = k0 + 16 * ct + lr;
#pragma unroll
        for (int r = 0; r < 4; r++) {
          int qglob = q0 + 16 * w + lk * 4 + r;
          if (kglob > qglob) s[ct][r] = -3.0e38f;
        }
      }
    }

    // online softmax (rows live in (lk,reg); cols across 16 lanes x 4 ct)
    float rm[4];
#pragma unroll
    for (int r = 0; r < 4; r++) {
      rm[r] = fmaxf(fmaxf(s[0][r], s[1][r]), fmaxf(s[2][r], s[3][r]));
#pragma unroll
      for (int off = 1; off < 16; off <<= 1)
        rm[r] = fmaxf(rm[r], __shfl_xor(rm[r], off));
    }
    float p[4][4];
#pragma unroll
    for (int r = 0; r < 4; r++) {
      float mn = fmaxf(m_[r], rm[r]);
      float corr = exp2f((m_[r] - mn) * C);
      float sum = 0.f;
#pragma unroll
      for (int ct = 0; ct < 4; ct++) {
        float pe = exp2f((s[ct][r] - mn) * C);
        p[ct][r] = pe;
        sum += pe;
      }
#pragma unroll
      for (int off = 1; off < 16; off <<= 1) sum += __shfl_xor(sum, off);
      l_[r] = l_[r] * corr + sum;
      m_[r] = mn;
#pragma unroll
      for (int ct = 0; ct < 4; ct++) o[ct][r] *= corr;
    }

    // P -> LDS (bf16), per-wave region
#pragma unroll
    for (int ct = 0; ct < 4; ct++)
#pragma unroll
      for (int r = 0; r < 4; r++)
        Ps[w][lk * 4 + r][16 * ct + lr] = f2bf(p[ct][r]);

    // O += P V  (A = P [q][kv], B = V [kv][d] read from V^T rows)
    bf16x8 pf0 = ldb8(&Ps[w][lr][lk * 8]);
    bf16x8 pf1 = ldb8(&Ps[w][lr][lk * 8 + 32]);
#pragma unroll
    for (int ct = 0; ct < 4; ct++) {
      bf16x8 vf0 = ldb8(&Vs[16 * ct + lr][lk * 8]);
      bf16x8 vf1 = ldb8(&Vs[16 * ct + lr][lk * 8 + 32]);
      o[ct] = mfma16(pf0, vf0, o[ct]);
      o[ct] = mfma16(pf1, vf1, o[ct]);
    }
    __syncthreads();
  }

  // normalize + store to (b, t, h*64+d) bf16
  int h = bh & 15, b = bh >> 4;
#pragma unroll
  for (int r = 0; r < 4; r++) {
    float inv = 1.0f / l_[r];
    int t = q0 + 16 * w + lk * 4 + r;
#pragma unroll
    for (int ct = 0; ct < 4; ct++) {
      og[((size_t)b * 2048 + t) * 1024 + h * 64 + 16 * ct + lr] = f2bf(o[ct][r] * inv);
    }
  }
}

// ---------------- Output GEMM (8192x1024x1024), fp32 out ----------------
__global__ __launch_bounds__(256) void gemm_out(
    const u16* __restrict__ ab, const u16* __restrict__ wb, float* __restrict__ out) {
  __shared__ u16 As[128][72];
  __shared__ u16 Bs[128][72];
  int tid = threadIdx.x, lane = tid & 63, w = tid >> 6;
  int wm = w >> 1, wn = w & 1;
  int lr = lane & 15, lk = lane >> 4;
  int m0 = blockIdx.y * 128, n0 = blockIdx.x * 128;

  f32x4 acc[4][4] = {};

  for (int k0 = 0; k0 < 1024; k0 += 64) {
#pragma unroll
    for (int i = 0; i < 4; i++) {
      int c = tid + 256 * i;
      int r = c >> 3, col = (c & 7) * 8;
      *reinterpret_cast<u16x8*>(&As[r][col]) =
          *reinterpret_cast<const u16x8*>(&ab[(size_t)(m0 + r) * 1024 + k0 + col]);
      *reinterpret_cast<u16x8*>(&Bs[r][col]) =
          *reinterpret_cast<const u16x8*>(&wb[(size_t)(n0 + r) * 1024 + k0 + col]);
    }
    __syncthreads();
#pragma unroll
    for (int kk = 0; kk < 2; kk++) {
      bf16x8 af[4], bfr[4];
#pragma unroll
      for (int mt = 0; mt < 4; mt++) af[mt]  = ldb8(&As[64 * wm + 16 * mt + lr][lk * 8 + 32 * kk]);
#pragma unroll
      for (int nt = 0; nt < 4; nt++) bfr[nt] = ldb8(&Bs[64 * wn + 16 * nt + lr][lk * 8 + 32 * kk]);
#pragma unroll
      for (int mt = 0; mt < 4; mt++)
#pragma unroll
        for (int nt = 0; nt < 4; nt++)
          acc[mt][nt] = mfma16(af[mt], bfr[nt], acc[mt][nt]);
    }
    __syncthreads();
  }

#pragma unroll
  for (int nt = 0; nt < 4; nt++) {
    int col = n0 + 64 * wn + 16 * nt + lr;
#pragma unroll
    for (int mt = 0; mt < 4; mt++) {
      int Mb = m0 + 64 * wm + 16 * mt + lk * 4;
#pragma unroll
      for (int r = 0; r < 4; r++) {
        out[(size_t)(Mb + r) * 1024 + col] = acc[mt][nt][r];
      }
    }
  }
}

// ---------------- launcher ----------------
extern "C" void kernel_launch(void* const* d_in, const int* in_sizes, int n_in,
                              void* d_out, int out_size, void* d_ws, size_t ws_size,
                              hipStream_t stream) {
  const float* x    = (const float*)d_in[0];
  const float* Wqkv = (const float*)d_in[2];
  const float* Wout = (const float*)d_in[3];
  float* out = (float*)d_out;
  char* ws = (char*)d_ws;

  u16* x_bf    = (u16*)(ws + 0);            // 16 MB
  u16* wqkv_bf = (u16*)(ws + 16777216);     // 6 MB
  u16* wout_bf = (u16*)(ws + 23068672);     // 2 MB
  u16* q_buf   = (u16*)(ws + 25165824);     // 16 MB  (b,h,t,d) rope'd
  u16* k_buf   = (u16*)(ws + 41943040);     // 16 MB  (b,h,t,d) rope'd
  u16* v_buf   = (u16*)(ws + 58720256);     // 16 MB  (b,h,t,d)
  u16* vt_buf  = (u16*)(ws + 75497472);     // 16 MB  (b,h,d,t)
  u16* a_out   = (u16*)(ws + 92274688);     // 16 MB  (b,t,h*64+d)
  float* cost  = (float*)(ws + 109051904);  // 256 KB
  float* sint  = (float*)(ws + 109314048);  // 256 KB

  cvt_bf16<<<2048, 256, 0, stream>>>(x, x_bf, 8388608 / 4);
  cvt_bf16<<<768, 256, 0, stream>>>(Wqkv, wqkv_bf, 3145728 / 4);
  cvt_bf16<<<256, 256, 0, stream>>>(Wout, wout_bf, 1048576 / 4);
  rope_tab<<<256, 256, 0, stream>>>(cost, sint);
  gemm_qkv<<<dim3(24, 64), 256, 0, stream>>>(x_bf, wqkv_bf, q_buf, k_buf, v_buf, cost, sint);
  transpose_v<<<dim3(32, 64), 256, 0, stream>>>(v_buf, vt_buf);
  attn_fwd<<<dim3(32, 64), 256, 0, stream>>>(q_buf, k_buf, vt_buf, a_out);
  gemm_out<<<dim3(8, 64), 256, 0, stream>>>(a_out, wout_bf, out);
}

// Round 2
// 292.020 us; speedup vs baseline: 1.3543x; 1.3543x over previous
//
#include <hip/hip_runtime.h>

typedef unsigned short u16;
typedef unsigned int   u32;
typedef __bf16 bf16;
typedef bf16  bf16x8 __attribute__((ext_vector_type(8)));
typedef u16   u16x8  __attribute__((ext_vector_type(8)));
typedef u32   u32x4  __attribute__((ext_vector_type(4)));
typedef float f32x4  __attribute__((ext_vector_type(4)));
typedef float f32x16 __attribute__((ext_vector_type(16)));

__device__ __forceinline__ u16 f2bf(float f) {
  u32 u = __builtin_bit_cast(u32, f);
  u32 r = u + 0x7fffu + ((u >> 16) & 1u);
  return (u16)(r >> 16);
}

__device__ __forceinline__ u32 cvtpk(float lo, float hi) {
  u32 r;
  asm("v_cvt_pk_bf16_f32 %0, %1, %2" : "=v"(r) : "v"(lo), "v"(hi));
  return r;
}

__device__ __forceinline__ bf16x8 ldb8(const u16* p) {
  return __builtin_bit_cast(bf16x8, *reinterpret_cast<const u16x8*>(p));
}

__device__ __forceinline__ f32x4 mfma16(bf16x8 a, bf16x8 b, f32x4 c) {
  return __builtin_amdgcn_mfma_f32_16x16x32_bf16(a, b, c, 0, 0, 0);
}

__device__ __forceinline__ f32x16 mfma32(bf16x8 a, bf16x8 b, f32x16 c) {
  return __builtin_amdgcn_mfma_f32_32x32x16_bf16(a, b, c, 0, 0, 0);
}

__device__ __forceinline__ void gl_lds16(const void* g, void* l) {
  __builtin_amdgcn_global_load_lds(
      (const __attribute__((address_space(1))) void*)g,
      (__attribute__((address_space(3))) void*)l, 16, 0, 0);
}

// stages a 128x64 u16 tile (16 KB) from row-major global (ld = 1024 u16)
__device__ __forceinline__ void stage128x64(const u16* gbase, u16* lds, int tid) {
#pragma unroll
  for (int rd = 0; rd < 4; rd++) {
    int o = rd * 4096 + tid * 16;       // byte offset in tile
    int row = o >> 7, colb = o & 127;
    gl_lds16((const char*)gbase + (size_t)row * 2048 + colb, (char*)lds + o);
  }
}

// ---------------- fp32 -> bf16 conversion ----------------
__global__ void cvt_bf16(const float* __restrict__ in, u16* __restrict__ out, int n4) {
  int stride = gridDim.x * blockDim.x;
  for (int i = blockIdx.x * blockDim.x + threadIdx.x; i < n4; i += stride) {
    float4 f = reinterpret_cast<const float4*>(in)[i];
    ushort4 o;
    o.x = f2bf(f.x); o.y = f2bf(f.y); o.z = f2bf(f.z); o.w = f2bf(f.w);
    reinterpret_cast<ushort4*>(out)[i] = o;
  }
}

// ---------------- RoPE tables: [2048][32] cos/sin ----------------
__global__ void rope_tab(float* __restrict__ ct, float* __restrict__ st) {
  int idx = blockIdx.x * 256 + threadIdx.x;   // 65536 total
  int t = idx >> 5, i = idx & 31;
  float theta = exp2f(-(float)i * 0.4152410118609203f);
  float ang = (float)t * theta;
  ct[idx] = cosf(ang);
  st[idx] = sinf(ang);
}

// ---------------- QKV GEMM (8192x3072x1024) + fused RoPE epilogue ----------------
__global__ __launch_bounds__(256) void gemm_qkv(
    const u16* __restrict__ xb, const u16* __restrict__ wb,
    u16* __restrict__ qb, u16* __restrict__ kb, u16* __restrict__ vb,
    const float* __restrict__ cost, const float* __restrict__ sint) {
  __shared__ u16 As[128 * 64];
  __shared__ u16 Bs[128 * 64];
  int tid = threadIdx.x, lane = tid & 63, w = tid >> 6;
  int wm = w >> 1, wn = w & 1;
  int lr = lane & 15, lk = lane >> 4;
  int m0 = blockIdx.y * 128, n0 = blockIdx.x * 128;

  f32x4 acc[4][4] = {};

  for (int k0 = 0; k0 < 1024; k0 += 64) {
    stage128x64(xb + (size_t)m0 * 1024 + k0, As, tid);
    stage128x64(wb + (size_t)n0 * 1024 + k0, Bs, tid);
    asm volatile("s_waitcnt vmcnt(0)" ::: "memory");
    __syncthreads();
#pragma unroll
    for (int kk = 0; kk < 2; kk++) {
      bf16x8 af[4], bfr[4];
#pragma unroll
      for (int mt = 0; mt < 4; mt++) af[mt]  = ldb8(&As[(64 * wm + 16 * mt + lr) * 64 + lk * 8 + 32 * kk]);
#pragma unroll
      for (int nt = 0; nt < 4; nt++) bfr[nt] = ldb8(&Bs[(64 * wn + 16 * nt + lr) * 64 + lk * 8 + 32 * kk]);
#pragma unroll
      for (int mt = 0; mt < 4; mt++)
#pragma unroll
        for (int nt = 0; nt < 4; nt++)
          acc[mt][nt] = mfma16(af[mt], bfr[nt], acc[mt][nt]);
    }
    __syncthreads();
  }

  // epilogue: C/D layout col = lane&15, row = (lane>>4)*4 + reg
#pragma unroll
  for (int nt = 0; nt < 4; nt++) {
    int col = n0 + 64 * wn + 16 * nt + lr;
    int sec = col >> 10;            // 0=q 1=k 2=v
    int cc = col & 1023;
    int h = cc >> 6, d = cc & 63;
    u16* buf = (sec == 0) ? qb : ((sec == 1) ? kb : vb);
#pragma unroll
    for (int mt = 0; mt < 4; mt++) {
      int Mb = m0 + 64 * wm + 16 * mt + lk * 4;
#pragma unroll
      for (int r = 0; r < 4; r++) {
        int M = Mb + r;
        int b = M >> 11, t = M & 2047;
        float val = acc[mt][nt][r];
        float par = __shfl_xor(val, 1);
        float res;
        if (sec < 2) {
          float c_ = cost[t * 32 + (d >> 1)];
          float s_ = sint[t * 32 + (d >> 1)];
          res = (d & 1) ? (val * c_ + par * s_) : (val * c_ - par * s_);
        } else {
          res = val;
        }
        buf[((size_t)(b * 16 + h) * 2048 + t) * 64 + d] = f2bf(res);
      }
    }
  }
}

// ---------------- V transpose: (bh, t, d) -> (bh, d, t) ----------------
__global__ __launch_bounds__(256) void transpose_v(const u16* __restrict__ v_buf,
                                                   u16* __restrict__ vt_buf) {
  __shared__ u16 tile[64][72];
  int bh = blockIdx.y, t0 = blockIdx.x * 64;
  const u16* src = v_buf + ((size_t)bh * 2048 + t0) * 64;
#pragma unroll
  for (int i = 0; i < 2; i++) {
    int c = threadIdx.x + 256 * i;
    int r = c >> 3, col = (c & 7) * 8;
    *reinterpret_cast<u16x8*>(&tile[r][col]) =
        *reinterpret_cast<const u16x8*>(&src[r * 64 + col]);
  }
  __syncthreads();
  u16* dst = vt_buf + (size_t)bh * 64 * 2048 + t0;
#pragma unroll
  for (int i = 0; i < 2; i++) {
    int c = threadIdx.x + 256 * i;
    int d = c >> 3, tt = (c & 7) * 8;
    u16x8 o;
#pragma unroll
    for (int j = 0; j < 8; j++) o[j] = tile[tt + j][d];
    *reinterpret_cast<u16x8*>(&dst[(size_t)d * 2048 + tt]) = o;
  }
}

// ---------------- Flash attention, swapped-QK^T 32x32 MFMA, no LDS, no barriers ----
// One wave owns q-tile pair (i, 63-i): uniform 65 KV-steps per wave.
// S^T = mfma(A=K, B=Q): lane holds S[kv set][q = lane&31] -> softmax lane-local
// O^T = mfma(A=V^T, B=P^T): lane holds O[d set][q = lane&31] -> rescale lane-local
__global__ __launch_bounds__(256) void attn_fwd(
    const u16* __restrict__ qg, const u16* __restrict__ kg,
    const u16* __restrict__ vtg, u16* __restrict__ og) {
  int tid = threadIdx.x, lane = tid & 63, w = tid >> 6;
  int l31 = lane & 31;
  int hi = lane >> 5;                 // 0 or 1
  int hoff = hi ? 8 : 0;
  // XCD swizzle: 8 blocks per bh land on one XCD (512 blocks, 512%8==0)
  int blk = (blockIdx.x & 7) * 64 + (blockIdx.x >> 3);
  int pairIdx = blk * 4 + w;
  int bh = pairIdx >> 5, ip = pairIdx & 31;
  const u16* qb  = qg  + (size_t)bh * 2048 * 64;
  const u16* kb  = kg  + (size_t)bh * 2048 * 64;
  const u16* vtb = vtg + (size_t)bh * 64 * 2048;
  int hh = bh & 15, b = bh >> 4;
  const float C = 0.18033688011112042f;   // 0.125 / ln(2)

#pragma unroll 1
  for (int half = 0; half < 2; half++) {
    int qt = half ? (63 - ip) : ip;
    int q0 = qt * 32;
    int qrow = q0 + l31;
    bf16x8 qf[4];
#pragma unroll
    for (int s = 0; s < 4; s++)
      qf[s] = ldb8(&qb[(size_t)qrow * 64 + 16 * s + hoff]);

    f32x16 o0 = {}, o1 = {};
    float m_ = -3.0e38f, l_ = 0.f;

#pragma unroll 1
    for (int kt = 0; kt <= qt; kt++) {
      int k0 = kt * 32;
      // V^T fragments early (hide L2 latency under QK + softmax)
      bf16x8 vf00 = ldb8(&vtb[(size_t)(l31)      * 2048 + k0 + hoff]);
      bf16x8 vf01 = ldb8(&vtb[(size_t)(l31)      * 2048 + k0 + 16 + hoff]);
      bf16x8 vf10 = ldb8(&vtb[(size_t)(32 + l31) * 2048 + k0 + hoff]);
      bf16x8 vf11 = ldb8(&vtb[(size_t)(32 + l31) * 2048 + k0 + 16 + hoff]);

      f32x16 sT = {};
#pragma unroll
      for (int s = 0; s < 4; s++) {
        bf16x8 kf = ldb8(&kb[(size_t)(k0 + l31) * 64 + 16 * s + hoff]);
        sT = mfma32(kf, qf[s], sT);
      }
      if (kt == qt) {   // causal mask on diagonal tile
#pragma unroll
        for (int r = 0; r < 16; r++) {
          int kvg = k0 + (r & 3) + 8 * (r >> 2) + 4 * hi;
          if (kvg > qrow) sT[r] = -3.0e38f;
        }
      }
      // row max (15 fmax tree + 1 cross-half exchange)
      float a0 = fmaxf(fmaxf(sT[0], sT[1]),  fmaxf(sT[2], sT[3]));
      float a1 = fmaxf(fmaxf(sT[4], sT[5]),  fmaxf(sT[6], sT[7]));
      float a2 = fmaxf(fmaxf(sT[8], sT[9]),  fmaxf(sT[10], sT[11]));
      float a3 = fmaxf(fmaxf(sT[12], sT[13]), fmaxf(sT[14], sT[15]));
      float pm = fmaxf(fmaxf(a0, a1), fmaxf(a2, a3));
      pm = fmaxf(pm, __shfl_xor(pm, 32));
      float mn = fmaxf(m_, pm);
      float corr = exp2f((m_ - mn) * C);
      float p[16];
#pragma unroll
      for (int r = 0; r < 16; r++) p[r] = exp2f((sT[r] - mn) * C);
      float r0 = (p[0] + p[1]) + (p[2] + p[3]);
      float r1 = (p[4] + p[5]) + (p[6] + p[7]);
      float r2 = (p[8] + p[9]) + (p[10] + p[11]);
      float r3 = (p[12] + p[13]) + (p[14] + p[15]);
      float rs = (r0 + r1) + (r2 + r3);
      rs += __shfl_xor(rs, 32);
      l_ = l_ * corr + rs;
      m_ = mn;
      o0 *= corr; o1 *= corr;

      // pack P to bf16 pairs; exchange across lane halves
      u32 c0 = cvtpk(p[0], p[1]),   c1 = cvtpk(p[2], p[3]);
      u32 c2 = cvtpk(p[4], p[5]),   c3 = cvtpk(p[6], p[7]);
      u32 c4 = cvtpk(p[8], p[9]),   c5 = cvtpk(p[10], p[11]);
      u32 c6 = cvtpk(p[12], p[13]), c7 = cvtpk(p[14], p[15]);
      u32 x0 = __shfl_xor((int)c0, 32), x1 = __shfl_xor((int)c1, 32);
      u32 x2 = __shfl_xor((int)c2, 32), x3 = __shfl_xor((int)c3, 32);
      u32 x4 = __shfl_xor((int)c4, 32), x5 = __shfl_xor((int)c5, 32);
      u32 x6 = __shfl_xor((int)c6, 32), x7 = __shfl_xor((int)c7, 32);
      // B-frag (P^T): k-chunk0 = kv 0..15, chunk1 = kv 16..31
      u32x4 w0 = { hi ? x2 : c0, hi ? x3 : c1, hi ? c2 : x0, hi ? c3 : x1 };
      u32x4 w1 = { hi ? x6 : c4, hi ? x7 : c5, hi ? c6 : x4, hi ? c7 : x5 };
      bf16x8 pf0 = __builtin_bit_cast(bf16x8, w0);
      bf16x8 pf1 = __builtin_bit_cast(bf16x8, w1);

      // O^T += V^T * P^T
      o0 = mfma32(vf00, pf0, o0);
      o0 = mfma32(vf01, pf1, o0);
      o1 = mfma32(vf10, pf0, o1);
      o1 = mfma32(vf11, pf1, o1);
    }

    float inv = 1.0f / l_;
    size_t base = ((size_t)b * 2048 + qrow) * 1024 + hh * 64;
#pragma unroll
    for (int db = 0; db < 2; db++) {
      f32x16 oo = db ? o1 : o0;
#pragma unroll
      for (int r = 0; r < 16; r += 2) {
        int d = db * 32 + (r & 3) + 8 * (r >> 2) + 4 * hi;
        u32 pk_ = cvtpk(oo[r] * inv, oo[r + 1] * inv);
        *reinterpret_cast<u32*>(&og[base + d]) = pk_;
      }
    }
  }
}

// ---------------- Output GEMM (8192x1024x1024), fp32 out ----------------
__global__ __launch_bounds__(256) void gemm_out(
    const u16* __restrict__ ab, const u16* __restrict__ wb, float* __restrict__ out) {
  __shared__ u16 As[128 * 64];
  __shared__ u16 Bs[128 * 64];
  int tid = threadIdx.x, lane = tid & 63, w = tid >> 6;
  int wm = w >> 1, wn = w & 1;
  int lr = lane & 15, lk = lane >> 4;
  int m0 = blockIdx.y * 128, n0 = blockIdx.x * 128;

  f32x4 acc[4][4] = {};

  for (int k0 = 0; k0 < 1024; k0 += 64) {
    stage128x64(ab + (size_t)m0 * 1024 + k0, As, tid);
    stage128x64(wb + (size_t)n0 * 1024 + k0, Bs, tid);
    asm volatile("s_waitcnt vmcnt(0)" ::: "memory");
    __syncthreads();
#pragma unroll
    for (int kk = 0; kk < 2; kk++) {
      bf16x8 af[4], bfr[4];
#pragma unroll
      for (int mt = 0; mt < 4; mt++) af[mt]  = ldb8(&As[(64 * wm + 16 * mt + lr) * 64 + lk * 8 + 32 * kk]);
#pragma unroll
      for (int nt = 0; nt < 4; nt++) bfr[nt] = ldb8(&Bs[(64 * wn + 16 * nt + lr) * 64 + lk * 8 + 32 * kk]);
#pragma unroll
      for (int mt = 0; mt < 4; mt++)
#pragma unroll
        for (int nt = 0; nt < 4; nt++)
          acc[mt][nt] = mfma16(af[mt], bfr[nt], acc[mt][nt]);
    }
    __syncthreads();
  }

#pragma unroll
  for (int nt = 0; nt < 4; nt++) {
    int col = n0 + 64 * wn + 16 * nt + lr;
#pragma unroll
    for (int mt = 0; mt < 4; mt++) {
      int Mb = m0 + 64 * wm + 16 * mt + lk * 4;
#pragma unroll
      for (int r = 0; r < 4; r++) {
        out[(size_t)(Mb + r) * 1024 + col] = acc[mt][nt][r];
      }
    }
  }
}

// ---------------- launcher ----------------
extern "C" void kernel_launch(void* const* d_in, const int* in_sizes, int n_in,
                              void* d_out, int out_size, void* d_ws, size_t ws_size,
                              hipStream_t stream) {
  const float* x    = (const float*)d_in[0];
  const float* Wqkv = (const float*)d_in[2];
  const float* Wout = (const float*)d_in[3];
  float* out = (float*)d_out;
  char* ws = (char*)d_ws;

  u16* x_bf    = (u16*)(ws + 0);            // 16 MB
  u16* wqkv_bf = (u16*)(ws + 16777216);     // 6 MB
  u16* wout_bf = (u16*)(ws + 23068672);     // 2 MB
  u16* q_buf   = (u16*)(ws + 25165824);     // 16 MB  (b,h,t,d) rope'd
  u16* k_buf   = (u16*)(ws + 41943040);     // 16 MB  (b,h,t,d) rope'd
  u16* v_buf   = (u16*)(ws + 58720256);     // 16 MB  (b,h,t,d)
  u16* vt_buf  = (u16*)(ws + 75497472);     // 16 MB  (b,h,d,t)
  u16* a_out   = (u16*)(ws + 92274688);     // 16 MB  (b,t,h*64+d)
  float* cost  = (float*)(ws + 109051904);  // 256 KB
  float* sint  = (float*)(ws + 109314048);  // 256 KB

  cvt_bf16<<<2048, 256, 0, stream>>>(x, x_bf, 8388608 / 4);
  cvt_bf16<<<768, 256, 0, stream>>>(Wqkv, wqkv_bf, 3145728 / 4);
  cvt_bf16<<<256, 256, 0, stream>>>(Wout, wout_bf, 1048576 / 4);
  rope_tab<<<256, 256, 0, stream>>>(cost, sint);
  gemm_qkv<<<dim3(24, 64), 256, 0, stream>>>(x_bf, wqkv_bf, q_buf, k_buf, v_buf, cost, sint);
  transpose_v<<<dim3(32, 64), 256, 0, stream>>>(v_buf, vt_buf);
  attn_fwd<<<512, 256, 0, stream>>>(q_buf, k_buf, vt_buf, a_out);
  gemm_out<<<dim3(8, 64), 256, 0, stream>>>(a_out, wout_bf, out);
}

// Round 4
// 268.567 us; speedup vs baseline: 1.4725x; 1.0873x over previous
//
#include <hip/hip_runtime.h>

typedef unsigned short u16;
typedef unsigned int   u32;
typedef __bf16 bf16;
typedef bf16  bf16x8 __attribute__((ext_vector_type(8)));
typedef u16   u16x8  __attribute__((ext_vector_type(8)));
typedef u32   u32x4  __attribute__((ext_vector_type(4)));
typedef float f32x4  __attribute__((ext_vector_type(4)));
typedef float f32x16 __attribute__((ext_vector_type(16)));

__device__ __forceinline__ u16 f2bf(float f) {
  u32 u = __builtin_bit_cast(u32, f);
  u32 r = u + 0x7fffu + ((u >> 16) & 1u);
  return (u16)(r >> 16);
}

__device__ __forceinline__ u32 cvtpk(float lo, float hi) {
  u32 r;
  asm("v_cvt_pk_bf16_f32 %0, %1, %2" : "=v"(r) : "v"(lo), "v"(hi));
  return r;
}

__device__ __forceinline__ bf16x8 ldb8(const u16* p) {
  return __builtin_bit_cast(bf16x8, *reinterpret_cast<const u16x8*>(p));
}

__device__ __forceinline__ f32x4 mfma16(bf16x8 a, bf16x8 b, f32x4 c) {
  return __builtin_amdgcn_mfma_f32_16x16x32_bf16(a, b, c, 0, 0, 0);
}

__device__ __forceinline__ f32x16 mfma32(bf16x8 a, bf16x8 b, f32x16 c) {
  return __builtin_amdgcn_mfma_f32_32x32x16_bf16(a, b, c, 0, 0, 0);
}

__device__ __forceinline__ void gl_lds16(const void* g, void* l) {
  __builtin_amdgcn_global_load_lds(
      (const __attribute__((address_space(1))) void*)g,
      (__attribute__((address_space(3))) void*)l, 16, 0, 0);
}

__device__ __forceinline__ void stage128x64(const u16* gbase, u16* lds, int tid) {
#pragma unroll
  for (int rd = 0; rd < 4; rd++) {
    int o = rd * 4096 + tid * 16;
    int row = o >> 7, colb = o & 127;
    gl_lds16((const char*)gbase + (size_t)row * 2048 + colb, (char*)lds + o);
  }
}

// ---------------- fp32 -> bf16 conversion ----------------
__global__ void cvt_bf16(const float* __restrict__ in, u16* __restrict__ out, int n4) {
  int stride = gridDim.x * blockDim.x;
  for (int i = blockIdx.x * blockDim.x + threadIdx.x; i < n4; i += stride) {
    float4 f = reinterpret_cast<const float4*>(in)[i];
    ushort4 o;
    o.x = f2bf(f.x); o.y = f2bf(f.y); o.z = f2bf(f.z); o.w = f2bf(f.w);
    reinterpret_cast<ushort4*>(out)[i] = o;
  }
}

// ---------------- RoPE tables: [2048][32] cos/sin ----------------
__global__ void rope_tab(float* __restrict__ ct, float* __restrict__ st) {
  int idx = blockIdx.x * 256 + threadIdx.x;
  int t = idx >> 5, i = idx & 31;
  float theta = exp2f(-(float)i * 0.4152410118609203f);
  float ang = (float)t * theta;
  ct[idx] = cosf(ang);
  st[idx] = sinf(ang);
}

// ---------------- QKV GEMM + fused RoPE + Q-prescale + direct V^T ----------------
// q is pre-scaled by 0.125/ln2 so attention softmax works in exp2 domain for free.
// V section writes transposed (bh, d, t) directly.
__global__ __launch_bounds__(256) void gemm_qkv(
    const u16* __restrict__ xb, const u16* __restrict__ wb,
    u16* __restrict__ qb, u16* __restrict__ kb, u16* __restrict__ vtb,
    const float* __restrict__ cost, const float* __restrict__ sint) {
  __shared__ u16 As[128 * 64];
  __shared__ u16 Bs[128 * 64];
  int tid = threadIdx.x, lane = tid & 63, w = tid >> 6;
  int wm = w >> 1, wn = w & 1;
  int lr = lane & 15, lk = lane >> 4;
  int m0 = blockIdx.y * 128, n0 = blockIdx.x * 128;

  f32x4 acc[4][4] = {};

  for (int k0 = 0; k0 < 1024; k0 += 64) {
    stage128x64(xb + (size_t)m0 * 1024 + k0, As, tid);
    stage128x64(wb + (size_t)n0 * 1024 + k0, Bs, tid);
    asm volatile("s_waitcnt vmcnt(0)" ::: "memory");
    __syncthreads();
#pragma unroll
    for (int kk = 0; kk < 2; kk++) {
      bf16x8 af[4], bfr[4];
#pragma unroll
      for (int mt = 0; mt < 4; mt++) af[mt]  = ldb8(&As[(64 * wm + 16 * mt + lr) * 64 + lk * 8 + 32 * kk]);
#pragma unroll
      for (int nt = 0; nt < 4; nt++) bfr[nt] = ldb8(&Bs[(64 * wn + 16 * nt + lr) * 64 + lk * 8 + 32 * kk]);
#pragma unroll
      for (int mt = 0; mt < 4; mt++)
#pragma unroll
        for (int nt = 0; nt < 4; nt++)
          acc[mt][nt] = mfma16(af[mt], bfr[nt], acc[mt][nt]);
    }
    __syncthreads();
  }

  const float CQ = 0.18033688011112042f;   // 0.125 / ln(2)
#pragma unroll
  for (int nt = 0; nt < 4; nt++) {
    int col = n0 + 64 * wn + 16 * nt + lr;
    int sec = col >> 10;            // 0=q 1=k 2=v
    int cc = col & 1023;
    int h = cc >> 6, d = cc & 63;
    if (sec < 2) {
      u16* buf = (sec == 0) ? qb : kb;
      float scale = (sec == 0) ? CQ : 1.0f;
#pragma unroll
      for (int mt = 0; mt < 4; mt++) {
        int Mb = m0 + 64 * wm + 16 * mt + lk * 4;
#pragma unroll
        for (int r = 0; r < 4; r++) {
          int M = Mb + r;
          int b = M >> 11, t = M & 2047;
          float val = acc[mt][nt][r];
          float par = __shfl_xor(val, 1);
          float c_ = cost[t * 32 + (d >> 1)];
          float s_ = sint[t * 32 + (d >> 1)];
          float res = (d & 1) ? (val * c_ + par * s_) : (val * c_ - par * s_);
          buf[((size_t)(b * 16 + h) * 2048 + t) * 64 + d] = f2bf(res * scale);
        }
      }
    } else {
      // V -> (b,h,d,t), 4 consecutive t packed per store
#pragma unroll
      for (int mt = 0; mt < 4; mt++) {
        int Mb = m0 + 64 * wm + 16 * mt + lk * 4;
        int b = Mb >> 11, t = Mb & 2047;
        ushort4 pk;
        pk.x = f2bf(acc[mt][nt][0]); pk.y = f2bf(acc[mt][nt][1]);
        pk.z = f2bf(acc[mt][nt][2]); pk.w = f2bf(acc[mt][nt][3]);
        *reinterpret_cast<ushort4*>(
            &vtb[((size_t)(b * 16 + h) * 64 + d) * 2048 + t]) = pk;
      }
    }
  }
}

// ---------------- Flash attention: 1 wave/block, swapped-QK^T, shfl_xor, defer-max --
// Wave owns q-tile qt = 63 - (blk>>6), bh = blk & 63 (LPT order).
// Q pre-scaled by 0.125/ln2 -> softmax entirely in exp2 domain.
__global__ __launch_bounds__(64, 3) void attn_fwd(
    const u16* __restrict__ qg, const u16* __restrict__ kg,
    const u16* __restrict__ vtg, u16* __restrict__ og) {
  int lane = threadIdx.x;
  int l31 = lane & 31;
  int hi = lane >> 5;
  int hoff = hi ? 8 : 0;
  int blk = blockIdx.x;
  int qt = 63 - (blk >> 6);
  int bh = blk & 63;
  const u16* qb  = qg  + (size_t)bh * 2048 * 64;
  const u16* kb  = kg  + (size_t)bh * 2048 * 64;
  const u16* vtb = vtg + (size_t)bh * 64 * 2048;
  int hh = bh & 15, b = bh >> 4;

  int q0 = qt * 32;
  int qrow = q0 + l31;
  bf16x8 qf[4];
#pragma unroll
  for (int s = 0; s < 4; s++)
    qf[s] = ldb8(&qb[(size_t)qrow * 64 + 16 * s + hoff]);

  f32x16 o0 = {}, o1 = {};
  float m_ = -3.0e38f, l_ = 0.f;

#pragma unroll 1
  for (int kt = 0; kt <= qt; kt++) {
    int k0 = kt * 32;
    // V^T fragments early (latency hidden under QK + softmax)
    bf16x8 vf00 = ldb8(&vtb[(size_t)(l31)      * 2048 + k0 + hoff]);
    bf16x8 vf01 = ldb8(&vtb[(size_t)(l31)      * 2048 + k0 + 16 + hoff]);
    bf16x8 vf10 = ldb8(&vtb[(size_t)(32 + l31) * 2048 + k0 + hoff]);
    bf16x8 vf11 = ldb8(&vtb[(size_t)(32 + l31) * 2048 + k0 + 16 + hoff]);

    f32x16 sT = {};
#pragma unroll
    for (int s = 0; s < 4; s++) {
      bf16x8 kf = ldb8(&kb[(size_t)(k0 + l31) * 64 + 16 * s + hoff]);
      sT = mfma32(kf, qf[s], sT);
    }
    if (kt == qt) {   // causal mask on diagonal tile
#pragma unroll
      for (int r = 0; r < 16; r++) {
        int kvg = k0 + (r & 3) + 8 * (r >> 2) + 4 * hi;
        if (kvg > qrow) sT[r] = -3.0e38f;
      }
    }
    // row max: 15-op tree + 1 cross-half shfl
    float a0 = fmaxf(fmaxf(sT[0], sT[1]),  fmaxf(sT[2], sT[3]));
    float a1 = fmaxf(fmaxf(sT[4], sT[5]),  fmaxf(sT[6], sT[7]));
    float a2 = fmaxf(fmaxf(sT[8], sT[9]),  fmaxf(sT[10], sT[11]));
    float a3 = fmaxf(fmaxf(sT[12], sT[13]), fmaxf(sT[14], sT[15]));
    float pm = fmaxf(fmaxf(a0, a1), fmaxf(a2, a3));
    pm = fmaxf(pm, __shfl_xor(pm, 32));

    // defer-max (T13): only rescale when max grew by > 8 (exp2 domain, P <= 256)
    if (__any(pm > m_ + 8.0f)) {
      float mn = fmaxf(m_, pm);
      float corr = exp2f(m_ - mn);
      l_ *= corr;
      o0 *= corr; o1 *= corr;
      m_ = mn;
    }

    float p[16];
#pragma unroll
    for (int r = 0; r < 16; r++) p[r] = exp2f(sT[r] - m_);
    float r0 = (p[0] + p[1]) + (p[2] + p[3]);
    float r1 = (p[4] + p[5]) + (p[6] + p[7]);
    float r2 = (p[8] + p[9]) + (p[10] + p[11]);
    float r3 = (p[12] + p[13]) + (p[14] + p[15]);
    float rs = (r0 + r1) + (r2 + r3);
    rs += __shfl_xor(rs, 32);
    l_ += rs;

    // pack P to bf16 pairs; exchange across lane halves (round-2-proven form)
    u32 c0 = cvtpk(p[0], p[1]),   c1 = cvtpk(p[2], p[3]);
    u32 c2 = cvtpk(p[4], p[5]),   c3 = cvtpk(p[6], p[7]);
    u32 c4 = cvtpk(p[8], p[9]),   c5 = cvtpk(p[10], p[11]);
    u32 c6 = cvtpk(p[12], p[13]), c7 = cvtpk(p[14], p[15]);
    u32 x0 = __shfl_xor((int)c0, 32), x1 = __shfl_xor((int)c1, 32);
    u32 x2 = __shfl_xor((int)c2, 32), x3 = __shfl_xor((int)c3, 32);
    u32 x4 = __shfl_xor((int)c4, 32), x5 = __shfl_xor((int)c5, 32);
    u32 x6 = __shfl_xor((int)c6, 32), x7 = __shfl_xor((int)c7, 32);
    u32x4 w0 = { hi ? x2 : c0, hi ? x3 : c1, hi ? c2 : x0, hi ? c3 : x1 };
    u32x4 w1 = { hi ? x6 : c4, hi ? x7 : c5, hi ? c6 : x4, hi ? c7 : x5 };
    bf16x8 pf0 = __builtin_bit_cast(bf16x8, w0);
    bf16x8 pf1 = __builtin_bit_cast(bf16x8, w1);

    // O^T += V^T * P^T
    o0 = mfma32(vf00, pf0, o0);
    o0 = mfma32(vf01, pf1, o0);
    o1 = mfma32(vf10, pf0, o1);
    o1 = mfma32(vf11, pf1, o1);
  }

  float inv = 1.0f / l_;
  size_t base = ((size_t)b * 2048 + qrow) * 1024 + hh * 64;
#pragma unroll
  for (int db = 0; db < 2; db++) {
    f32x16 oo = db ? o1 : o0;
#pragma unroll
    for (int r = 0; r < 16; r += 2) {
      int d = db * 32 + (r & 3) + 8 * (r >> 2) + 4 * hi;
      u32 pk_ = cvtpk(oo[r] * inv, oo[r + 1] * inv);
      *reinterpret_cast<u32*>(&og[base + d]) = pk_;
    }
  }
}

// ---------------- Output GEMM (8192x1024x1024), fp32 out ----------------
__global__ __launch_bounds__(256) void gemm_out(
    const u16* __restrict__ ab, const u16* __restrict__ wb, float* __restrict__ out) {
  __shared__ u16 As[128 * 64];
  __shared__ u16 Bs[128 * 64];
  int tid = threadIdx.x, lane = tid & 63, w = tid >> 6;
  int wm = w >> 1, wn = w & 1;
  int lr = lane & 15, lk = lane >> 4;
  int m0 = blockIdx.y * 128, n0 = blockIdx.x * 128;

  f32x4 acc[4][4] = {};

  for (int k0 = 0; k0 < 1024; k0 += 64) {
    stage128x64(ab + (size_t)m0 * 1024 + k0, As, tid);
    stage128x64(wb + (size_t)n0 * 1024 + k0, Bs, tid);
    asm volatile("s_waitcnt vmcnt(0)" ::: "memory");
    __syncthreads();
#pragma unroll
    for (int kk = 0; kk < 2; kk++) {
      bf16x8 af[4], bfr[4];
#pragma unroll
      for (int mt = 0; mt < 4; mt++) af[mt]  = ldb8(&As[(64 * wm + 16 * mt + lr) * 64 + lk * 8 + 32 * kk]);
#pragma unroll
      for (int nt = 0; nt < 4; nt++) bfr[nt] = ldb8(&Bs[(64 * wn + 16 * nt + lr) * 64 + lk * 8 + 32 * kk]);
#pragma unroll
      for (int mt = 0; mt < 4; mt++)
#pragma unroll
        for (int nt = 0; nt < 4; nt++)
          acc[mt][nt] = mfma16(af[mt], bfr[nt], acc[mt][nt]);
    }
    __syncthreads();
  }

#pragma unroll
  for (int nt = 0; nt < 4; nt++) {
    int col = n0 + 64 * wn + 16 * nt + lr;
#pragma unroll
    for (int mt = 0; mt < 4; mt++) {
      int Mb = m0 + 64 * wm + 16 * mt + lk * 4;
#pragma unroll
      for (int r = 0; r < 4; r++) {
        out[(size_t)(Mb + r) * 1024 + col] = acc[mt][nt][r];
      }
    }
  }
}

// ---------------- launcher ----------------
extern "C" void kernel_launch(void* const* d_in, const int* in_sizes, int n_in,
                              void* d_out, int out_size, void* d_ws, size_t ws_size,
                              hipStream_t stream) {
  const float* x    = (const float*)d_in[0];
  const float* Wqkv = (const float*)d_in[2];
  const float* Wout = (const float*)d_in[3];
  float* out = (float*)d_out;
  char* ws = (char*)d_ws;

  u16* x_bf    = (u16*)(ws + 0);            // 16 MB
  u16* wqkv_bf = (u16*)(ws + 16777216);     // 6 MB
  u16* wout_bf = (u16*)(ws + 23068672);     // 2 MB
  u16* q_buf   = (u16*)(ws + 25165824);     // 16 MB  (b,h,t,d) rope'd, pre-scaled
  u16* k_buf   = (u16*)(ws + 41943040);     // 16 MB  (b,h,t,d) rope'd
  u16* vt_buf  = (u16*)(ws + 75497472);     // 16 MB  (b,h,d,t)
  u16* a_out   = (u16*)(ws + 92274688);     // 16 MB  (b,t,h*64+d)
  float* cost  = (float*)(ws + 109051904);  // 256 KB
  float* sint  = (float*)(ws + 109314048);  // 256 KB

  cvt_bf16<<<2048, 256, 0, stream>>>(x, x_bf, 8388608 / 4);
  cvt_bf16<<<768, 256, 0, stream>>>(Wqkv, wqkv_bf, 3145728 / 4);
  cvt_bf16<<<256, 256, 0, stream>>>(Wout, wout_bf, 1048576 / 4);
  rope_tab<<<256, 256, 0, stream>>>(cost, sint);
  gemm_qkv<<<dim3(24, 64), 256, 0, stream>>>(x_bf, wqkv_bf, q_buf, k_buf, vt_buf, cost, sint);
  attn_fwd<<<4096, 64, 0, stream>>>(q_buf, k_buf, vt_buf, a_out);
  gemm_out<<<dim3(8, 64), 256, 0, stream>>>(a_out, wout_bf, out);
}